// Round 1
// baseline (811.862 us; speedup 1.0000x reference)
//
#include <hip/hip_runtime.h>
#include <hip/hip_bf16.h>

#define DIM   1024
#define NATT  90      // K*K + K = 81 + 9
#define SEQL  4096
#define NB    4
#define NTOK  16384   // NB * SEQL

// ---------- helpers ----------
static __device__ __forceinline__ unsigned short f2bf(float f) {
    unsigned int u = __float_as_uint(f);
    unsigned int r = (u + 0x7fffu + ((u >> 16) & 1u)) >> 16;   // RNE
    return (unsigned short)r;
}

typedef __attribute__((ext_vector_type(8))) short frag_ab;   // 8 x bf16
typedef __attribute__((ext_vector_type(4))) float frag_cd;   // 4 x f32

// ---------- stage 1: att = x @ w2^T + b2 -> coeff[9] + absum per token ----------
// block: 256 threads, 8 tokens/block, grid 2048
__global__ __launch_bounds__(256) void att_coeff_kernel(
    const float* __restrict__ x, const float* __restrict__ w2,
    const float* __restrict__ b2, float* __restrict__ cws)
{
    __shared__ float xs[8][DIM];
    __shared__ float att_s[8][NATT + 2];
    const int tid  = threadIdx.x;
    const int tok0 = blockIdx.x * 8;

    // load 8 x-rows into LDS (float4, coalesced)
    const float4* xv  = (const float4*)(x + (size_t)tok0 * DIM);
    float4*       xsv = (float4*)(&xs[0][0]);
    for (int i = tid; i < 8 * DIM / 4; i += 256) xsv[i] = xv[i];
    __syncthreads();

    const float4* w2v = (const float4*)w2;
    for (int o = tid; o < 8 * NATT; o += 256) {
        const int t = o / NATT;
        const int m = o - t * NATT;
        const float4* wr = w2v + m * (DIM / 4);
        float s = 0.f;
        #pragma unroll 4
        for (int i = 0; i < DIM / 4; ++i) {
            float4 w = wr[i];
            s += xs[t][i*4+0] * w.x + xs[t][i*4+1] * w.y
               + xs[t][i*4+2] * w.z + xs[t][i*4+3] * w.w;
        }
        att_s[t][m] = s + b2[m];
    }
    __syncthreads();

    // reduce: coeff[k] = sum_j sin(att[9k+j]);  absum = sum att[81..89]
    if (tid < 80) {
        const int t = tid / 10;
        const int j = tid - (tid / 10) * 10;
        float v = 0.f;
        if (j < 9) {
            #pragma unroll
            for (int jj = 0; jj < 9; ++jj) v += sinf(att_s[t][j * 9 + jj]);
        } else {
            #pragma unroll
            for (int k = 81; k < 90; ++k) v += att_s[t][k];
        }
        cws[(size_t)(tok0 + t) * 10 + j] = v;
    }
}

// ---------- wo -> bf16 ----------
__global__ __launch_bounds__(256) void cvt_wo_kernel(
    const float* __restrict__ wo, unsigned short* __restrict__ wob)
{
    const int i = blockIdx.x * 256 + threadIdx.x;   // float4 index, 262144 total
    float4 v = ((const float4*)wo)[i];
    union { unsigned short u[4]; uint2 v2; } p;
    p.u[0] = f2bf(v.x); p.u[1] = f2bf(v.y); p.u[2] = f2bf(v.z); p.u[3] = f2bf(v.w);
    ((uint2*)wob)[i] = p.v2;
}

// ---------- stage 2: y (stencil) -> bf16 ----------
// one block per token, 256 threads x float4 = 1024 dims
__global__ __launch_bounds__(256) void y_kernel(
    const float* __restrict__ x, const float* __restrict__ cws,
    unsigned short* __restrict__ ybf)
{
    __shared__ float c[10];
    const int tok = blockIdx.x;
    const int tid = threadIdx.x;
    if (tid < 10) c[tid] = cws[(size_t)tok * 10 + tid];
    __syncthreads();

    const int b = tok >> 12;      // / 4096
    const int l = tok & 4095;
    float4 acc;
    acc.x = acc.y = acc.z = acc.w = c[9];
    const float4* xv = (const float4*)x;
    #pragma unroll
    for (int k = 0; k < 9; ++k) {
        const int src = l + k - 4;
        if (src >= 0 && src < SEQL) {
            float4 v = xv[((size_t)(b * SEQL + src)) * (DIM / 4) + tid];
            const float ck = c[k];
            acc.x += ck * v.x; acc.y += ck * v.y;
            acc.z += ck * v.z; acc.w += ck * v.w;
        }
    }
    union { unsigned short u[4]; uint2 v2; } p;
    p.u[0] = f2bf(acc.x); p.u[1] = f2bf(acc.y); p.u[2] = f2bf(acc.z); p.u[3] = f2bf(acc.w);
    ((uint2*)ybf)[(size_t)tok * (DIM / 4) + tid] = p.v2;
}

// ---------- stage 3: out = y @ wo^T + bo  (bf16 MFMA, fp32 accum) ----------
#define BM 64
#define BN 64
#define BK 32
#define LDP 40   // padded row stride in bf16 units (80 B -> 2-way bank alias, free)

__global__ __launch_bounds__(256) void gemm_kernel(
    const unsigned short* __restrict__ A,   // y_bf  [16384][1024]
    const unsigned short* __restrict__ Bm,  // wo_bf [1024][1024]
    const float* __restrict__ bo,
    float* __restrict__ out)
{
    __shared__ unsigned short As[BM * LDP];
    __shared__ unsigned short Bs[BN * LDP];

    const int tid  = threadIdx.x;
    const int wave = tid >> 6;
    const int lane = tid & 63;
    const int wm   = (wave >> 1) * 32;      // wave row offset in tile
    const int wn   = (wave & 1) * 32;
    const int srow   = tid >> 2;            // staging row 0..63
    const int schunk = (tid & 3) * 8;       // bf16 col offset within BK
    const int m0 = blockIdx.x * BM;
    const int n0 = blockIdx.y * BN;

    const int fr = lane & 15;
    const int kg = (lane >> 4) * 8;

    frag_cd acc[2][2] = {};

    for (int k0 = 0; k0 < DIM; k0 += BK) {
        uint4 av = *(const uint4*)(A  + (size_t)(m0 + srow) * DIM + k0 + schunk);
        uint4 bv = *(const uint4*)(Bm + (size_t)(n0 + srow) * DIM + k0 + schunk);
        __syncthreads();   // previous iteration's ds_reads complete
        *(uint4*)(&As[srow * LDP + schunk]) = av;
        *(uint4*)(&Bs[srow * LDP + schunk]) = bv;
        __syncthreads();

        frag_ab a0 = *(const frag_ab*)(&As[(wm      + fr) * LDP + kg]);
        frag_ab a1 = *(const frag_ab*)(&As[(wm + 16 + fr) * LDP + kg]);
        frag_ab b0 = *(const frag_ab*)(&Bs[(wn      + fr) * LDP + kg]);
        frag_ab b1 = *(const frag_ab*)(&Bs[(wn + 16 + fr) * LDP + kg]);

        acc[0][0] = __builtin_amdgcn_mfma_f32_16x16x32_bf16(a0, b0, acc[0][0], 0, 0, 0);
        acc[0][1] = __builtin_amdgcn_mfma_f32_16x16x32_bf16(a0, b1, acc[0][1], 0, 0, 0);
        acc[1][0] = __builtin_amdgcn_mfma_f32_16x16x32_bf16(a1, b0, acc[1][0], 0, 0, 0);
        acc[1][1] = __builtin_amdgcn_mfma_f32_16x16x32_bf16(a1, b1, acc[1][1], 0, 0, 0);
    }

    // epilogue: D col = lane&15, row = (lane>>4)*4 + r  (m89/m91-verified)
    const int col   = lane & 15;
    const int rbase = (lane >> 4) * 4;
    #pragma unroll
    for (int i = 0; i < 2; ++i) {
        #pragma unroll
        for (int j = 0; j < 2; ++j) {
            const int n = n0 + wn + j * 16 + col;
            const float bias = bo[n];
            #pragma unroll
            for (int r = 0; r < 4; ++r) {
                const int m = m0 + wm + i * 16 + rbase + r;
                out[(size_t)m * DIM + n] = acc[i][j][r] + bias;
            }
        }
    }
}

// ---------- launch ----------
extern "C" void kernel_launch(void* const* d_in, const int* in_sizes, int n_in,
                              void* d_out, int out_size, void* d_ws, size_t ws_size,
                              hipStream_t stream) {
    const float* x  = (const float*)d_in[0];
    const float* w2 = (const float*)d_in[1];
    const float* b2 = (const float*)d_in[2];
    const float* wo = (const float*)d_in[3];
    const float* bo = (const float*)d_in[4];
    float* out = (float*)d_out;

    char* ws = (char*)d_ws;
    float*          cws = (float*)ws;                              // 16384*10*4   = 655,360 B
    unsigned short* wob = (unsigned short*)(ws + 655360);          // 1024*1024*2  = 2,097,152 B
    unsigned short* ybf = (unsigned short*)(ws + 655360 + 2097152);// 16384*1024*2 = 33,554,432 B

    att_coeff_kernel<<<NTOK / 8, 256, 0, stream>>>(x, w2, b2, cws);
    cvt_wo_kernel<<<(DIM * DIM / 4) / 256, 256, 0, stream>>>(wo, wob);
    y_kernel<<<NTOK, 256, 0, stream>>>(x, cws, ybf);
    gemm_kernel<<<dim3(NTOK / BM, DIM / BN), 256, 0, stream>>>(ybf, wob, bo, out);
}

// Round 2
// 194.216 us; speedup vs baseline: 4.1802x; 4.1802x over previous
//
#include <hip/hip_runtime.h>
#include <hip/hip_bf16.h>

#define DIM   1024
#define SEQL  4096
#define NTOK  16384
#define NATT  90
#define NATTP 96

typedef __attribute__((ext_vector_type(8))) short frag_ab;   // 8 x bf16
typedef __attribute__((ext_vector_type(4))) float frag_cd;   // 4 x f32

typedef unsigned int u32;
typedef const __attribute__((address_space(1))) u32* gp_t;
typedef __attribute__((address_space(3))) u32* lp_t;

static __device__ __forceinline__ unsigned short f2bf(float f) {
    unsigned int u = __float_as_uint(f);
    return (unsigned short)((u + 0x7fffu + ((u >> 16) & 1u)) >> 16);  // RNE
}
static __device__ __forceinline__ ushort4 f4tobf(float4 v) {
    ushort4 r; r.x = f2bf(v.x); r.y = f2bf(v.y); r.z = f2bf(v.z); r.w = f2bf(v.w);
    return r;
}

// ---------- stage 1: att = x @ w2^T + b2 -> coeff[9]+absum, MFMA version ----------
// block: 256 thr (4 waves), 64 tokens/block, grid 256
#define ABK  64
#define ALDP 72   // padded bf16 row stride: 144 B -> fr*36 dwords -> 2-way alias, free

__global__ __launch_bounds__(256) void att_coeff_kernel(
    const float* __restrict__ x, const float* __restrict__ w2,
    const float* __restrict__ b2, float* __restrict__ cws)
{
    __shared__ unsigned short xs[64 * ALDP];
    __shared__ unsigned short ws[NATTP * ALDP];
    __shared__ float att_s[64][NATTP];
    __shared__ float b2s[NATTP];

    const int tid  = threadIdx.x;
    const int wave = tid >> 6, lane = tid & 63;
    const int fr = lane & 15, kg = (lane >> 4) * 8;
    const int tok0 = blockIdx.x * 64;

    if (tid < NATTP) b2s[tid] = (tid < NATT) ? b2[tid] : 0.f;

    frag_cd acc[6] = {};

    for (int k0 = 0; k0 < DIM; k0 += ABK) {
        __syncthreads();   // previous iteration's frag reads complete
        // stage x tile: 64 rows x 64 cols, f32 -> bf16
        #pragma unroll
        for (int i = 0; i < 4; ++i) {
            int c = tid + i * 256;                 // 0..1023
            int row = c >> 4, col = (c & 15) * 4;
            float4 v = *(const float4*)(x + (size_t)(tok0 + row) * DIM + k0 + col);
            *(ushort4*)(&xs[row * ALDP + col]) = f4tobf(v);
        }
        // stage w2 tile: 96 rows x 64 cols (rows >= 90 zeroed)
        #pragma unroll
        for (int i = 0; i < 6; ++i) {
            int c = tid + i * 256;                 // 0..1535
            int row = c >> 4, col = (c & 15) * 4;
            float4 v = make_float4(0.f, 0.f, 0.f, 0.f);
            if (row < NATT) v = *(const float4*)(w2 + (size_t)row * DIM + k0 + col);
            *(ushort4*)(&ws[row * ALDP + col]) = f4tobf(v);
        }
        __syncthreads();
        #pragma unroll
        for (int s = 0; s < 2; ++s) {
            frag_ab a = *(const frag_ab*)(&xs[(wave * 16 + fr) * ALDP + s * 32 + kg]);
            #pragma unroll
            for (int f = 0; f < 6; ++f) {
                frag_ab b = *(const frag_ab*)(&ws[(f * 16 + fr) * ALDP + s * 32 + kg]);
                acc[f] = __builtin_amdgcn_mfma_f32_16x16x32_bf16(a, b, acc[f], 0, 0, 0);
            }
        }
    }

    // epilogue: att tile -> LDS (+b2), D layout col=lane&15, row=(lane>>4)*4+r
    const int col = lane & 15, rb = (lane >> 4) * 4;
    #pragma unroll
    for (int f = 0; f < 6; ++f)
        #pragma unroll
        for (int r = 0; r < 4; ++r)
            att_s[wave * 16 + rb + r][f * 16 + col] = acc[f][r] + b2s[f * 16 + col];
    __syncthreads();

    // coeff[k] = sum_j sin(att[9k+j]);  absum = sum att[81..89]
    for (int o = tid; o < 640; o += 256) {
        int t = o / 10, j = o - (o / 10) * 10;
        float s = 0.f;
        if (j < 9) {
            #pragma unroll
            for (int jj = 0; jj < 9; ++jj) s += sinf(att_s[t][j * 9 + jj]);
        } else {
            #pragma unroll
            for (int m = NATT - 9; m < NATT; ++m) s += att_s[t][m];
        }
        cws[(size_t)(tok0 + t) * 10 + j] = s;
    }
}

// ---------- wo -> bf16 ----------
__global__ __launch_bounds__(256) void cvt_wo_kernel(
    const float* __restrict__ wo, unsigned short* __restrict__ wob)
{
    const int i = blockIdx.x * 256 + threadIdx.x;   // float4 index, 262144 total
    float4 v = ((const float4*)wo)[i];
    ushort4 p = f4tobf(v);
    *(ushort4*)(wob + (size_t)i * 4) = p;
}

// ---------- stage 2: y (stencil) -> bf16 ----------
__global__ __launch_bounds__(256) void y_kernel(
    const float* __restrict__ x, const float* __restrict__ cws,
    unsigned short* __restrict__ ybf)
{
    __shared__ float c[10];
    const int tok = blockIdx.x;
    const int tid = threadIdx.x;
    if (tid < 10) c[tid] = cws[(size_t)tok * 10 + tid];
    __syncthreads();

    const int b = tok >> 12;
    const int l = tok & 4095;
    float4 acc;
    acc.x = acc.y = acc.z = acc.w = c[9];
    const float4* xv = (const float4*)x;
    #pragma unroll
    for (int k = 0; k < 9; ++k) {
        const int src = l + k - 4;
        if (src >= 0 && src < SEQL) {
            float4 v = xv[((size_t)(b * SEQL + src)) * (DIM / 4) + tid];
            const float ck = c[k];
            acc.x += ck * v.x; acc.y += ck * v.y;
            acc.z += ck * v.z; acc.w += ck * v.w;
        }
    }
    *(ushort4*)(ybf + (size_t)tok * DIM + tid * 4) = f4tobf(acc);
}

// ---------- stage 3: out = y @ wo^T + bo  (m97 structure + XOR swizzle) ----------
#define BM 128
#define BN 128
#define BK 64

__global__ __launch_bounds__(256) void gemm_kernel(
    const unsigned short* __restrict__ A,   // y_bf  [16384][1024]
    const unsigned short* __restrict__ Bm,  // wo_bf [1024][1024] (row = out col)
    const float* __restrict__ bo,
    float* __restrict__ out)
{
    __shared__ unsigned short As[BM * BK];   // 16 KB, linear+swizzled content
    __shared__ unsigned short Bs[BN * BK];   // 16 KB

    const int tid  = threadIdx.x;
    const int wave = tid >> 6, lane = tid & 63;
    const int fr = lane & 15, kq = lane >> 4;        // kq = 0..3
    const int wm = (wave >> 1) * 64, wn = (wave & 1) * 64;
    const int m0 = blockIdx.y * BM, n0 = blockIdx.x * BN;

    // staging geometry: chunk = 16 B = 8 bf16; 8 chunks per row (BK=64)
    // LDS chunk (row,p) holds global col-chunk (p ^ (row&7))  [both-sides swizzle]
    const int cbase = wave * 4;   // 4 calls/wave for A, 4 for B

    frag_cd acc[4][4] = {};

    for (int k0 = 0; k0 < DIM; k0 += BK) {
        #pragma unroll
        for (int i = 0; i < 4; ++i) {
            int c = (cbase + i) * 64 + lane;         // 0..1023
            int row = c >> 3, p = c & 7;
            int scol = (p ^ (row & 7)) * 8;          // pre-swizzled global source
            __builtin_amdgcn_global_load_lds(
                (gp_t)(A + (size_t)(m0 + row) * DIM + k0 + scol),
                (lp_t)(&As[(cbase + i) * 64 * 8]), 16, 0, 0);
            __builtin_amdgcn_global_load_lds(
                (gp_t)(Bm + (size_t)(n0 + row) * DIM + k0 + scol),
                (lp_t)(&Bs[(cbase + i) * 64 * 8]), 16, 0, 0);
        }
        __syncthreads();   // vmcnt(0) drained by compiler before barrier

        #pragma unroll
        for (int s = 0; s < 2; ++s) {
            const int j = s * 4 + kq;                // k-chunk index 0..7
            frag_ab a[4], b[4];
            #pragma unroll
            for (int m = 0; m < 4; ++m) {
                int row = wm + m * 16 + fr;
                a[m] = *(const frag_ab*)(&As[row * 64 + ((j ^ (row & 7)) * 8)]);
            }
            #pragma unroll
            for (int n = 0; n < 4; ++n) {
                int row = wn + n * 16 + fr;
                b[n] = *(const frag_ab*)(&Bs[row * 64 + ((j ^ (row & 7)) * 8)]);
            }
            #pragma unroll
            for (int m = 0; m < 4; ++m)
                #pragma unroll
                for (int n = 0; n < 4; ++n)
                    acc[m][n] = __builtin_amdgcn_mfma_f32_16x16x32_bf16(
                        a[m], b[n], acc[m][n], 0, 0, 0);
        }
        __syncthreads();   // all reads done before next stage overwrites
    }

    // epilogue
    const int colb = lane & 15, rb = (lane >> 4) * 4;
    #pragma unroll
    for (int n = 0; n < 4; ++n) {
        const int col = n0 + wn + n * 16 + colb;
        const float bias = bo[col];
        #pragma unroll
        for (int m = 0; m < 4; ++m) {
            #pragma unroll
            for (int r = 0; r < 4; ++r) {
                const int row = m0 + wm + m * 16 + rb + r;
                out[(size_t)row * DIM + col] = acc[m][n][r] + bias;
            }
        }
    }
}

// ---------- launch ----------
extern "C" void kernel_launch(void* const* d_in, const int* in_sizes, int n_in,
                              void* d_out, int out_size, void* d_ws, size_t ws_size,
                              hipStream_t stream) {
    const float* x  = (const float*)d_in[0];
    const float* w2 = (const float*)d_in[1];
    const float* b2 = (const float*)d_in[2];
    const float* wo = (const float*)d_in[3];
    const float* bo = (const float*)d_in[4];
    float* out = (float*)d_out;

    char* ws = (char*)d_ws;
    float*          cws = (float*)ws;                               // 655,360 B
    unsigned short* wob = (unsigned short*)(ws + 655360);           // 2 MB
    unsigned short* ybf = (unsigned short*)(ws + 655360 + 2097152); // 32 MB

    att_coeff_kernel<<<NTOK / 64, 256, 0, stream>>>(x, w2, b2, cws);
    cvt_wo_kernel<<<(DIM * DIM / 4) / 256, 256, 0, stream>>>(wo, wob);
    y_kernel<<<NTOK, 256, 0, stream>>>(x, cws, ybf);
    gemm_kernel<<<dim3(DIM / BN, NTOK / BM), 256, 0, stream>>>(ybf, wob, bo, out);
}

// Round 3
// 117.909 us; speedup vs baseline: 6.8855x; 1.6472x over previous
//
#include <hip/hip_runtime.h>
#include <hip/hip_bf16.h>

#define DIM   1024
#define SEQL  4096
#define NTOK  16384
#define NATT  90
#define NATTP 96

typedef __attribute__((ext_vector_type(8))) short frag_ab;   // 8 x bf16
typedef __attribute__((ext_vector_type(4))) float frag_cd;   // 4 x f32

typedef unsigned int u32;
typedef const __attribute__((address_space(1))) u32* gp_t;
typedef __attribute__((address_space(3))) u32* lp_t;

static __device__ __forceinline__ unsigned short f2bf(float f) {
    unsigned int u = __float_as_uint(f);
    return (unsigned short)((u + 0x7fffu + ((u >> 16) & 1u)) >> 16);  // RNE
}
static __device__ __forceinline__ ushort4 f4tobf(float4 v) {
    ushort4 r; r.x = f2bf(v.x); r.y = f2bf(v.y); r.z = f2bf(v.z); r.w = f2bf(v.w);
    return r;
}

// ---------- stage 1: att = x @ w2^T + b2 -> coeff[9]+absum, MFMA version ----------
#define ABK  64
#define ALDP 72   // padded bf16 row stride: 144 B -> 2-way alias, free

__global__ __launch_bounds__(256) void att_coeff_kernel(
    const float* __restrict__ x, const float* __restrict__ w2,
    const float* __restrict__ b2, float* __restrict__ cws)
{
    __shared__ unsigned short xs[64 * ALDP];
    __shared__ unsigned short ws[NATTP * ALDP];
    __shared__ float att_s[64][NATTP];
    __shared__ float b2s[NATTP];

    const int tid  = threadIdx.x;
    const int wave = tid >> 6, lane = tid & 63;
    const int fr = lane & 15, kg = (lane >> 4) * 8;
    const int tok0 = blockIdx.x * 64;

    if (tid < NATTP) b2s[tid] = (tid < NATT) ? b2[tid] : 0.f;

    frag_cd acc[6] = {};

    for (int k0 = 0; k0 < DIM; k0 += ABK) {
        __syncthreads();
        #pragma unroll
        for (int i = 0; i < 4; ++i) {
            int c = tid + i * 256;
            int row = c >> 4, col = (c & 15) * 4;
            float4 v = *(const float4*)(x + (size_t)(tok0 + row) * DIM + k0 + col);
            *(ushort4*)(&xs[row * ALDP + col]) = f4tobf(v);
        }
        #pragma unroll
        for (int i = 0; i < 6; ++i) {
            int c = tid + i * 256;
            int row = c >> 4, col = (c & 15) * 4;
            float4 v = make_float4(0.f, 0.f, 0.f, 0.f);
            if (row < NATT) v = *(const float4*)(w2 + (size_t)row * DIM + k0 + col);
            *(ushort4*)(&ws[row * ALDP + col]) = f4tobf(v);
        }
        __syncthreads();
        #pragma unroll
        for (int s = 0; s < 2; ++s) {
            frag_ab a = *(const frag_ab*)(&xs[(wave * 16 + fr) * ALDP + s * 32 + kg]);
            #pragma unroll
            for (int f = 0; f < 6; ++f) {
                frag_ab b = *(const frag_ab*)(&ws[(f * 16 + fr) * ALDP + s * 32 + kg]);
                acc[f] = __builtin_amdgcn_mfma_f32_16x16x32_bf16(a, b, acc[f], 0, 0, 0);
            }
        }
    }

    const int col = lane & 15, rb = (lane >> 4) * 4;
    #pragma unroll
    for (int f = 0; f < 6; ++f)
        #pragma unroll
        for (int r = 0; r < 4; ++r)
            att_s[wave * 16 + rb + r][f * 16 + col] = acc[f][r] + b2s[f * 16 + col];
    __syncthreads();

    for (int o = tid; o < 640; o += 256) {
        int t = o / 10, j = o - (o / 10) * 10;
        float s = 0.f;
        if (j < 9) {
            #pragma unroll
            for (int jj = 0; jj < 9; ++jj) s += sinf(att_s[t][j * 9 + jj]);
        } else {
            #pragma unroll
            for (int m = NATT - 9; m < NATT; ++m) s += att_s[t][m];
        }
        cws[(size_t)(tok0 + t) * 10 + j] = s;
    }
}

// ---------- wo -> bf16 ----------
__global__ __launch_bounds__(256) void cvt_wo_kernel(
    const float* __restrict__ wo, unsigned short* __restrict__ wob)
{
    const int i = blockIdx.x * 256 + threadIdx.x;
    float4 v = ((const float4*)wo)[i];
    *(ushort4*)(wob + (size_t)i * 4) = f4tobf(v);
}

// ---------- stage 2: y stencil, rolling register window ----------
// block = 32 consecutive tokens x 1024 dims; thread owns one float4 dim-slice
#define TT 32

__global__ __launch_bounds__(256) void y_kernel(
    const float* __restrict__ x, const float* __restrict__ cws,
    unsigned short* __restrict__ ybf)
{
    __shared__ float c[TT][10];
    const int tid  = threadIdx.x;
    const int tok0 = blockIdx.x * TT;

    for (int i = tid; i < TT * 10; i += 256)
        c[i / 10][i % 10] = cws[(size_t)tok0 * 10 + i];
    __syncthreads();

    const int b  = tok0 >> 12;
    const int l0 = tok0 & 4095;
    const float4* xv = (const float4*)x + (size_t)b * SEQL * (DIM / 4) + tid;
    const float4 z4 = make_float4(0.f, 0.f, 0.f, 0.f);

    float4 w[9];
    #pragma unroll
    for (int k = 0; k < 8; ++k) {
        const int src = l0 + k - 4;
        w[k] = (src >= 0 && src < SEQL) ? xv[(size_t)src * (DIM / 4)] : z4;
    }

    ushort4* yp = (ushort4*)(ybf + (size_t)tok0 * DIM + tid * 4);

    #pragma unroll
    for (int t = 0; t < TT; ++t) {
        const int src = l0 + t + 4;
        w[8] = (src < SEQL) ? xv[(size_t)src * (DIM / 4)] : z4;

        float4 acc;
        acc.x = acc.y = acc.z = acc.w = c[t][9];
        #pragma unroll
        for (int k = 0; k < 9; ++k) {
            const float ck = c[t][k];
            acc.x += ck * w[k].x; acc.y += ck * w[k].y;
            acc.z += ck * w[k].z; acc.w += ck * w[k].w;
        }
        yp[(size_t)t * (DIM / 4)] = f4tobf(acc);

        #pragma unroll
        for (int k = 0; k < 8; ++k) w[k] = w[k + 1];
    }
}

// ---------- stage 3: out = y @ wo^T + bo  (m97 structure + XCD swizzle) ----------
#define BM 128
#define BN 128
#define BK 64

__global__ __launch_bounds__(256) void gemm_kernel(
    const unsigned short* __restrict__ A,   // y_bf  [16384][1024]
    const unsigned short* __restrict__ Bm,  // wo_bf [1024][1024] (row = out col)
    const float* __restrict__ bo,
    float* __restrict__ out)
{
    __shared__ unsigned short As[BM * BK];   // 16 KB
    __shared__ unsigned short Bs[BN * BK];   // 16 KB

    const int tid  = threadIdx.x;
    const int wave = tid >> 6, lane = tid & 63;
    const int fr = lane & 15, kq = lane >> 4;
    const int wm = (wave >> 1) * 64, wn = (wave & 1) * 64;

    // XCD-aware swizzle: 1024 tiles = 128 M x 8 N (N fast). XCD k owns 16 M-rows.
    const int bid = blockIdx.x;
    const int lid = (bid & 7) * 128 + (bid >> 3);
    const int m0  = (lid >> 3) * BM;
    const int n0  = (lid & 7) * BN;

    const int cbase = wave * 4;

    frag_cd acc[4][4] = {};

    for (int k0 = 0; k0 < DIM; k0 += BK) {
        #pragma unroll
        for (int i = 0; i < 4; ++i) {
            int c = (cbase + i) * 64 + lane;
            int row = c >> 3, p = c & 7;
            int scol = (p ^ (row & 7)) * 8;          // pre-swizzled global source
            __builtin_amdgcn_global_load_lds(
                (gp_t)(A + (size_t)(m0 + row) * DIM + k0 + scol),
                (lp_t)(&As[(cbase + i) * 64 * 8]), 16, 0, 0);
            __builtin_amdgcn_global_load_lds(
                (gp_t)(Bm + (size_t)(n0 + row) * DIM + k0 + scol),
                (lp_t)(&Bs[(cbase + i) * 64 * 8]), 16, 0, 0);
        }
        __syncthreads();

        #pragma unroll
        for (int s = 0; s < 2; ++s) {
            const int j = s * 4 + kq;
            frag_ab a[4], b[4];
            #pragma unroll
            for (int m = 0; m < 4; ++m) {
                int row = wm + m * 16 + fr;
                a[m] = *(const frag_ab*)(&As[row * 64 + ((j ^ (row & 7)) * 8)]);
            }
            #pragma unroll
            for (int n = 0; n < 4; ++n) {
                int row = wn + n * 16 + fr;
                b[n] = *(const frag_ab*)(&Bs[row * 64 + ((j ^ (row & 7)) * 8)]);
            }
            #pragma unroll
            for (int m = 0; m < 4; ++m)
                #pragma unroll
                for (int n = 0; n < 4; ++n)
                    acc[m][n] = __builtin_amdgcn_mfma_f32_16x16x32_bf16(
                        a[m], b[n], acc[m][n], 0, 0, 0);
        }
        __syncthreads();
    }

    const int colb = lane & 15, rb = (lane >> 4) * 4;
    #pragma unroll
    for (int n = 0; n < 4; ++n) {
        const int col = n0 + wn + n * 16 + colb;
        const float bias = bo[col];
        #pragma unroll
        for (int m = 0; m < 4; ++m) {
            #pragma unroll
            for (int r = 0; r < 4; ++r) {
                const int row = m0 + wm + m * 16 + rb + r;
                out[(size_t)row * DIM + col] = acc[m][n][r] + bias;
            }
        }
    }
}

// ---------- launch ----------
extern "C" void kernel_launch(void* const* d_in, const int* in_sizes, int n_in,
                              void* d_out, int out_size, void* d_ws, size_t ws_size,
                              hipStream_t stream) {
    const float* x  = (const float*)d_in[0];
    const float* w2 = (const float*)d_in[1];
    const float* b2 = (const float*)d_in[2];
    const float* wo = (const float*)d_in[3];
    const float* bo = (const float*)d_in[4];
    float* out = (float*)d_out;

    char* ws = (char*)d_ws;
    float*          cws = (float*)ws;                               // 655,360 B
    unsigned short* wob = (unsigned short*)(ws + 655360);           // 2 MB
    unsigned short* ybf = (unsigned short*)(ws + 655360 + 2097152); // 32 MB

    att_coeff_kernel<<<NTOK / 64, 256, 0, stream>>>(x, w2, b2, cws);
    cvt_wo_kernel<<<(DIM * DIM / 4) / 256, 256, 0, stream>>>(wo, wob);
    y_kernel<<<NTOK / TT, 256, 0, stream>>>(x, cws, ybf);
    gemm_kernel<<<NTOK / BM * (DIM / BN), 256, 0, stream>>>(ybf, wob, bo, out);
}

// Round 4
// 109.820 us; speedup vs baseline: 7.3927x; 1.0737x over previous
//
#include <hip/hip_runtime.h>
#include <hip/hip_bf16.h>

#define DIM   1024
#define SEQL  4096
#define NTOK  16384
#define NATT  90
#define NATTP 96

typedef __attribute__((ext_vector_type(8))) short frag_ab;   // 8 x bf16
typedef __attribute__((ext_vector_type(4))) float frag_cd;   // 4 x f32

typedef unsigned int u32;
typedef const __attribute__((address_space(1))) u32* gp_t;
typedef __attribute__((address_space(3))) u32* lp_t;

static __device__ __forceinline__ unsigned short f2bf(float f) {
    unsigned int u = __float_as_uint(f);
    return (unsigned short)((u + 0x7fffu + ((u >> 16) & 1u)) >> 16);  // RNE
}
static __device__ __forceinline__ ushort4 f4tobf(float4 v) {
    ushort4 r; r.x = f2bf(v.x); r.y = f2bf(v.y); r.z = f2bf(v.z); r.w = f2bf(v.w);
    return r;
}
static __device__ __forceinline__ frag_ab f8tofrag(float4 a, float4 b) {
    frag_ab f;
    f[0] = (short)f2bf(a.x); f[1] = (short)f2bf(a.y);
    f[2] = (short)f2bf(a.z); f[3] = (short)f2bf(a.w);
    f[4] = (short)f2bf(b.x); f[5] = (short)f2bf(b.y);
    f[6] = (short)f2bf(b.z); f[7] = (short)f2bf(b.w);
    return f;
}

// ---------- w2 -> bf16 (96 rows, zero-padded) ----------
__global__ __launch_bounds__(256) void cvt_w2_kernel(
    const float* __restrict__ w2, unsigned short* __restrict__ w2b)
{
    const int i = blockIdx.x * 256 + threadIdx.x;     // float4 idx, 96*1024/4 = 24576
    const int row = i >> 8;                           // 256 float4 per row
    float4 v = make_float4(0.f, 0.f, 0.f, 0.f);
    if (row < NATT) v = ((const float4*)w2)[i];
    *(ushort4*)(w2b + (size_t)i * 4) = f4tobf(v);
}

// ---------- stage 1: att = x @ w2b^T + b2 -> coeff[9]+absum ----------
// block = 16 tokens, 4 waves K-split (256 each); fragments direct global->VGPR
#define PSTR 98   // padded partial-row stride (floats): 4*98 % 32 == 8 -> conflict-free

__global__ __launch_bounds__(256) void att_coeff_kernel(
    const float* __restrict__ x, const unsigned short* __restrict__ w2b,
    const float* __restrict__ b2, float* __restrict__ cws)
{
    __shared__ float part[4 * 16 * PSTR];   // [wave][row][96(+pad)]
    __shared__ float summ[16 * NATTP];
    __shared__ float b2s[NATTP];

    const int tid  = threadIdx.x;
    const int wave = tid >> 6, lane = tid & 63;
    const int fr = lane & 15, kq = lane >> 4;
    const int tok0 = blockIdx.x * 16;

    if (tid < NATTP) b2s[tid] = (tid < NATT) ? b2[tid] : 0.f;

    frag_cd acc[6] = {};

    const float* xrow = x + (size_t)(tok0 + fr) * DIM + wave * 256 + kq * 8;
    const unsigned short* wrow = w2b + (size_t)fr * DIM + wave * 256 + kq * 8;

    #pragma unroll
    for (int kk = 0; kk < 8; ++kk) {
        float4 a0 = *(const float4*)(xrow + kk * 32);
        float4 a1 = *(const float4*)(xrow + kk * 32 + 4);
        frag_ab a = f8tofrag(a0, a1);
        #pragma unroll
        for (int f = 0; f < 6; ++f) {
            frag_ab b = *(const frag_ab*)(wrow + (size_t)f * 16 * DIM + kk * 32);
            acc[f] = __builtin_amdgcn_mfma_f32_16x16x32_bf16(a, b, acc[f], 0, 0, 0);
        }
    }

    // partials -> LDS.  D layout: col = lane&15, row = (lane>>4)*4 + r
    const int col = lane & 15, rb = (lane >> 4) * 4;
    #pragma unroll
    for (int f = 0; f < 6; ++f)
        #pragma unroll
        for (int r = 0; r < 4; ++r)
            part[(wave * 16 + rb + r) * PSTR + f * 16 + col] = acc[f][r];
    __syncthreads();

    // sum over the 4 K-slices, add bias
    for (int o = tid; o < 16 * NATTP; o += 256) {
        const int t = o / NATTP, m = o - (o / NATTP) * NATTP;
        float s = b2s[m];
        #pragma unroll
        for (int w = 0; w < 4; ++w) s += part[(w * 16 + t) * PSTR + m];
        summ[t * NATTP + m] = s;
    }
    __syncthreads();

    // coeff[k] = sum_j sin(att[9k+j]);  absum = sum att[81..89]
    if (tid < 160) {
        const int t = tid / 10, j = tid - (tid / 10) * 10;
        float s = 0.f;
        if (j < 9) {
            #pragma unroll
            for (int jj = 0; jj < 9; ++jj) s += sinf(summ[t * NATTP + j * 9 + jj]);
        } else {
            #pragma unroll
            for (int m = NATT - 9; m < NATT; ++m) s += summ[t * NATTP + m];
        }
        cws[(size_t)(tok0 + t) * 10 + j] = s;
    }
}

// ---------- wo -> bf16 ----------
__global__ __launch_bounds__(256) void cvt_wo_kernel(
    const float* __restrict__ wo, unsigned short* __restrict__ wob)
{
    const int i = blockIdx.x * 256 + threadIdx.x;
    float4 v = ((const float4*)wo)[i];
    *(ushort4*)(wob + (size_t)i * 4) = f4tobf(v);
}

// ---------- stage 2: y stencil, rolling register window ----------
#define TT 32

__global__ __launch_bounds__(256) void y_kernel(
    const float* __restrict__ x, const float* __restrict__ cws,
    unsigned short* __restrict__ ybf)
{
    __shared__ float c[TT][10];
    const int tid  = threadIdx.x;
    const int tok0 = blockIdx.x * TT;

    for (int i = tid; i < TT * 10; i += 256)
        c[i / 10][i % 10] = cws[(size_t)tok0 * 10 + i];
    __syncthreads();

    const int b  = tok0 >> 12;
    const int l0 = tok0 & 4095;
    const float4* xv = (const float4*)x + (size_t)b * SEQL * (DIM / 4) + tid;
    const float4 z4 = make_float4(0.f, 0.f, 0.f, 0.f);

    float4 w[9];
    #pragma unroll
    for (int k = 0; k < 8; ++k) {
        const int src = l0 + k - 4;
        w[k] = (src >= 0 && src < SEQL) ? xv[(size_t)src * (DIM / 4)] : z4;
    }

    ushort4* yp = (ushort4*)(ybf + (size_t)tok0 * DIM + tid * 4);

    #pragma unroll
    for (int t = 0; t < TT; ++t) {
        const int src = l0 + t + 4;
        w[8] = (src < SEQL) ? xv[(size_t)src * (DIM / 4)] : z4;

        float4 acc;
        acc.x = acc.y = acc.z = acc.w = c[t][9];
        #pragma unroll
        for (int k = 0; k < 9; ++k) {
            const float ck = c[t][k];
            acc.x += ck * w[k].x; acc.y += ck * w[k].y;
            acc.z += ck * w[k].z; acc.w += ck * w[k].w;
        }
        yp[(size_t)t * (DIM / 4)] = f4tobf(acc);

        #pragma unroll
        for (int k = 0; k < 8; ++k) w[k] = w[k + 1];
    }
}

// ---------- stage 3: out = y @ wo^T + bo  (m97 structure + XCD swizzle) ----------
#define BM 128
#define BN 128
#define BK 64

__global__ __launch_bounds__(256) void gemm_kernel(
    const unsigned short* __restrict__ A,   // y_bf  [16384][1024]
    const unsigned short* __restrict__ Bm,  // wo_bf [1024][1024] (row = out col)
    const float* __restrict__ bo,
    float* __restrict__ out)
{
    __shared__ unsigned short As[BM * BK];
    __shared__ unsigned short Bs[BN * BK];

    const int tid  = threadIdx.x;
    const int wave = tid >> 6, lane = tid & 63;
    const int fr = lane & 15, kq = lane >> 4;
    const int wm = (wave >> 1) * 64, wn = (wave & 1) * 64;

    // XCD-aware swizzle: 1024 tiles = 128 M x 8 N (N fast). XCD k owns 16 M-rows.
    const int bid = blockIdx.x;
    const int lid = (bid & 7) * 128 + (bid >> 3);
    const int m0  = (lid >> 3) * BM;
    const int n0  = (lid & 7) * BN;

    const int cbase = wave * 4;

    frag_cd acc[4][4] = {};

    for (int k0 = 0; k0 < DIM; k0 += BK) {
        #pragma unroll
        for (int i = 0; i < 4; ++i) {
            int c = (cbase + i) * 64 + lane;
            int row = c >> 3, p = c & 7;
            int scol = (p ^ (row & 7)) * 8;          // pre-swizzled global source
            __builtin_amdgcn_global_load_lds(
                (gp_t)(A + (size_t)(m0 + row) * DIM + k0 + scol),
                (lp_t)(&As[(cbase + i) * 64 * 8]), 16, 0, 0);
            __builtin_amdgcn_global_load_lds(
                (gp_t)(Bm + (size_t)(n0 + row) * DIM + k0 + scol),
                (lp_t)(&Bs[(cbase + i) * 64 * 8]), 16, 0, 0);
        }
        __syncthreads();

        #pragma unroll
        for (int s = 0; s < 2; ++s) {
            const int j = s * 4 + kq;
            frag_ab a[4], b[4];
            #pragma unroll
            for (int m = 0; m < 4; ++m) {
                int row = wm + m * 16 + fr;
                a[m] = *(const frag_ab*)(&As[row * 64 + ((j ^ (row & 7)) * 8)]);
            }
            #pragma unroll
            for (int n = 0; n < 4; ++n) {
                int row = wn + n * 16 + fr;
                b[n] = *(const frag_ab*)(&Bs[row * 64 + ((j ^ (row & 7)) * 8)]);
            }
            #pragma unroll
            for (int m = 0; m < 4; ++m)
                #pragma unroll
                for (int n = 0; n < 4; ++n)
                    acc[m][n] = __builtin_amdgcn_mfma_f32_16x16x32_bf16(
                        a[m], b[n], acc[m][n], 0, 0, 0);
        }
        __syncthreads();
    }

    const int colb = lane & 15, rb = (lane >> 4) * 4;
    #pragma unroll
    for (int n = 0; n < 4; ++n) {
        const int col = n0 + wn + n * 16 + colb;
        const float bias = bo[col];
        #pragma unroll
        for (int m = 0; m < 4; ++m) {
            #pragma unroll
            for (int r = 0; r < 4; ++r) {
                const int row = m0 + wm + m * 16 + rb + r;
                out[(size_t)row * DIM + col] = acc[m][n][r] + bias;
            }
        }
    }
}

// ---------- launch ----------
extern "C" void kernel_launch(void* const* d_in, const int* in_sizes, int n_in,
                              void* d_out, int out_size, void* d_ws, size_t ws_size,
                              hipStream_t stream) {
    const float* x  = (const float*)d_in[0];
    const float* w2 = (const float*)d_in[1];
    const float* b2 = (const float*)d_in[2];
    const float* wo = (const float*)d_in[3];
    const float* bo = (const float*)d_in[4];
    float* out = (float*)d_out;

    char* ws = (char*)d_ws;
    float*          cws = (float*)ws;                                // 655,360 B
    unsigned short* wob = (unsigned short*)(ws + 655360);            // 2 MB
    unsigned short* ybf = (unsigned short*)(ws + 655360 + 2097152);  // 32 MB
    unsigned short* w2b = (unsigned short*)(ws + 655360 + 2097152 + 33554432); // 192 KB

    cvt_w2_kernel<<<NATTP * DIM / 4 / 256, 256, 0, stream>>>(w2, w2b);
    cvt_wo_kernel<<<(DIM * DIM / 4) / 256, 256, 0, stream>>>(wo, wob);
    att_coeff_kernel<<<NTOK / 16, 256, 0, stream>>>(x, w2b, b2, cws);
    y_kernel<<<NTOK / TT, 256, 0, stream>>>(x, cws, ybf);
    gemm_kernel<<<NTOK / BM * (DIM / BN), 256, 0, stream>>>(ybf, wob, bo, out);
}

// Round 5
// 102.301 us; speedup vs baseline: 7.9360x; 1.0735x over previous
//
#include <hip/hip_runtime.h>
#include <hip/hip_bf16.h>

#define DIM   1024
#define SEQL  4096
#define NTOK  16384
#define NATT  90
#define NATTP 96

typedef __attribute__((ext_vector_type(8))) short frag_ab;   // 8 x bf16
typedef __attribute__((ext_vector_type(4))) float frag_cd;   // 4 x f32

typedef unsigned int u32;
typedef const __attribute__((address_space(1))) u32* gp_t;
typedef __attribute__((address_space(3))) u32* lp_t;

static __device__ __forceinline__ unsigned short f2bf(float f) {
    unsigned int u = __float_as_uint(f);
    return (unsigned short)((u + 0x7fffu + ((u >> 16) & 1u)) >> 16);  // RNE
}
static __device__ __forceinline__ ushort4 f4tobf(float4 v) {
    ushort4 r; r.x = f2bf(v.x); r.y = f2bf(v.y); r.z = f2bf(v.z); r.w = f2bf(v.w);
    return r;
}
static __device__ __forceinline__ frag_ab f8tofrag(float4 a, float4 b) {
    frag_ab f;
    f[0] = (short)f2bf(a.x); f[1] = (short)f2bf(a.y);
    f[2] = (short)f2bf(a.z); f[3] = (short)f2bf(a.w);
    f[4] = (short)f2bf(b.x); f[5] = (short)f2bf(b.y);
    f[6] = (short)f2bf(b.z); f[7] = (short)f2bf(b.w);
    return f;
}

// ---------- w2 -> bf16 (96 rows, zero-padded) ----------
__global__ __launch_bounds__(256) void cvt_w2_kernel(
    const float* __restrict__ w2, unsigned short* __restrict__ w2b)
{
    const int i = blockIdx.x * 256 + threadIdx.x;
    const int row = i >> 8;
    float4 v = make_float4(0.f, 0.f, 0.f, 0.f);
    if (row < NATT) v = ((const float4*)w2)[i];
    *(ushort4*)(w2b + (size_t)i * 4) = f4tobf(v);
}

// ---------- stage 1: att = x @ w2b^T + b2 -> coeff[9]+absum ----------
#define PSTR 98

__global__ __launch_bounds__(256) void att_coeff_kernel(
    const float* __restrict__ x, const unsigned short* __restrict__ w2b,
    const float* __restrict__ b2, float* __restrict__ cws)
{
    __shared__ float part[4 * 16 * PSTR];
    __shared__ float summ[16 * NATTP];
    __shared__ float b2s[NATTP];

    const int tid  = threadIdx.x;
    const int wave = tid >> 6, lane = tid & 63;
    const int fr = lane & 15, kq = lane >> 4;
    const int tok0 = blockIdx.x * 16;

    if (tid < NATTP) b2s[tid] = (tid < NATT) ? b2[tid] : 0.f;

    frag_cd acc[6] = {};

    const float* xrow = x + (size_t)(tok0 + fr) * DIM + wave * 256 + kq * 8;
    const unsigned short* wrow = w2b + (size_t)fr * DIM + wave * 256 + kq * 8;

    #pragma unroll
    for (int kk = 0; kk < 8; ++kk) {
        float4 a0 = *(const float4*)(xrow + kk * 32);
        float4 a1 = *(const float4*)(xrow + kk * 32 + 4);
        frag_ab a = f8tofrag(a0, a1);
        #pragma unroll
        for (int f = 0; f < 6; ++f) {
            frag_ab b = *(const frag_ab*)(wrow + (size_t)f * 16 * DIM + kk * 32);
            acc[f] = __builtin_amdgcn_mfma_f32_16x16x32_bf16(a, b, acc[f], 0, 0, 0);
        }
    }

    const int col = lane & 15, rb = (lane >> 4) * 4;
    #pragma unroll
    for (int f = 0; f < 6; ++f)
        #pragma unroll
        for (int r = 0; r < 4; ++r)
            part[(wave * 16 + rb + r) * PSTR + f * 16 + col] = acc[f][r];
    __syncthreads();

    for (int o = tid; o < 16 * NATTP; o += 256) {
        const int t = o / NATTP, m = o - (o / NATTP) * NATTP;
        float s = b2s[m];
        #pragma unroll
        for (int w = 0; w < 4; ++w) s += part[(w * 16 + t) * PSTR + m];
        summ[t * NATTP + m] = s;
    }
    __syncthreads();

    if (tid < 160) {
        const int t = tid / 10, j = tid - (tid / 10) * 10;
        float s = 0.f;
        if (j < 9) {
            #pragma unroll
            for (int jj = 0; jj < 9; ++jj) s += sinf(summ[t * NATTP + j * 9 + jj]);
        } else {
            #pragma unroll
            for (int m = NATT - 9; m < NATT; ++m) s += summ[t * NATTP + m];
        }
        cws[(size_t)(tok0 + t) * 10 + j] = s;
    }
}

// ---------- wo -> bf16 ----------
__global__ __launch_bounds__(256) void cvt_wo_kernel(
    const float* __restrict__ wo, unsigned short* __restrict__ wob)
{
    const int i = blockIdx.x * 256 + threadIdx.x;
    float4 v = ((const float4*)wo)[i];
    *(ushort4*)(wob + (size_t)i * 4) = f4tobf(v);
}

// ---------- stage 2: y stencil, rolling register window ----------
#define TT 32

__global__ __launch_bounds__(256) void y_kernel(
    const float* __restrict__ x, const float* __restrict__ cws,
    unsigned short* __restrict__ ybf)
{
    __shared__ float c[TT][10];
    const int tid  = threadIdx.x;
    const int tok0 = blockIdx.x * TT;

    for (int i = tid; i < TT * 10; i += 256)
        c[i / 10][i % 10] = cws[(size_t)tok0 * 10 + i];
    __syncthreads();

    const int b  = tok0 >> 12;
    const int l0 = tok0 & 4095;
    const float4* xv = (const float4*)x + (size_t)b * SEQL * (DIM / 4) + tid;
    const float4 z4 = make_float4(0.f, 0.f, 0.f, 0.f);

    float4 w[9];
    #pragma unroll
    for (int k = 0; k < 8; ++k) {
        const int src = l0 + k - 4;
        w[k] = (src >= 0 && src < SEQL) ? xv[(size_t)src * (DIM / 4)] : z4;
    }

    ushort4* yp = (ushort4*)(ybf + (size_t)tok0 * DIM + tid * 4);

    #pragma unroll
    for (int t = 0; t < TT; ++t) {
        const int src = l0 + t + 4;
        w[8] = (src < SEQL) ? xv[(size_t)src * (DIM / 4)] : z4;

        float4 acc;
        acc.x = acc.y = acc.z = acc.w = c[t][9];
        #pragma unroll
        for (int k = 0; k < 9; ++k) {
            const float ck = c[t][k];
            acc.x += ck * w[k].x; acc.y += ck * w[k].y;
            acc.z += ck * w[k].z; acc.w += ck * w[k].w;
        }
        yp[(size_t)t * (DIM / 4)] = f4tobf(acc);

        #pragma unroll
        for (int k = 0; k < 8; ++k) w[k] = w[k + 1];
    }
}

// ---------- stage 3: out = y @ wo^T + bo ----------
// 256x256 tile, BK=64, 8 waves (2Mx4N), double-buffered LDS, counted vmcnt.
#define GBM 256
#define GBN 256
#define GBK 64

// stage K-tile kt into LDS buffer d: 8 global_load_lds(16B) per thread
#define STAGE(d, kt)                                                           \
    {                                                                          \
        const int kc_ = (kt) * GBK;                                            \
        _Pragma("unroll")                                                      \
        for (int j_ = 0; j_ < 4; ++j_) {                                       \
            __builtin_amdgcn_global_load_lds(                                  \
                (gp_t)(A + (size_t)(m0 + srow[j_]) * DIM + kc_ + scol[j_]),    \
                (lp_t)(&As[d][(wave * 4 + j_) * 512]), 16, 0, 0);              \
            __builtin_amdgcn_global_load_lds(                                  \
                (gp_t)(Bm + (size_t)(n0 + srow[j_]) * DIM + kc_ + scol[j_]),   \
                (lp_t)(&Bs[d][(wave * 4 + j_) * 512]), 16, 0, 0);              \
        }                                                                      \
    }

#define READ_B(d)                                                              \
    _Pragma("unroll")                                                          \
    for (int ni = 0; ni < 4; ++ni) {                                           \
        int row = wn + ni * 16 + fr;                                           \
        bf0[ni] = *(const frag_ab*)(&As[0][0] + 0, &Bs[d][row * 64 + (((kq) ^ (row & 7)) * 8)]); \
    }

__global__ __launch_bounds__(512, 2) void gemm_kernel(
    const unsigned short* __restrict__ A,   // y_bf  [16384][1024]
    const unsigned short* __restrict__ Bm,  // wo_bf [1024][1024] (row = out col)
    const float* __restrict__ bo,
    float* __restrict__ out)
{
    __shared__ unsigned short As[2][GBM * GBK];   // 2 x 32 KB
    __shared__ unsigned short Bs[2][GBN * GBK];   // 2 x 32 KB

    const int tid  = threadIdx.x;
    const int wave = tid >> 6, lane = tid & 63;
    const int fr = lane & 15, kq = lane >> 4;
    const int wm = (wave >> 2) * 128;    // 0 or 128
    const int wn = (wave & 3) * 64;      // 0,64,128,192

    // bijective XCD swizzle: 256 blocks = 8 XCDs x 32; XCD owns 8 contiguous M-panels
    const int bid = blockIdx.x;
    const int lid = (bid & 7) * 32 + (bid >> 3);
    const int m0  = (lid >> 2) * GBM;
    const int n0  = (lid & 3) * GBN;

    // staging geometry: chunk block b = wave*4+j covers rows b*8..b*8+7
    int srow[4], scol[4];
    #pragma unroll
    for (int j = 0; j < 4; ++j) {
        int ci = (wave * 4 + j) * 64 + lane;
        int row = ci >> 3;
        srow[j] = row;
        scol[j] = ((ci & 7) ^ (row & 7)) * 8;    // pre-swizzled global source
    }

    frag_cd acc[8][4] = {};

    STAGE(0, 0);
    STAGE(1, 1);

    for (int kt = 0; kt < 15; ++kt) {
        const int d = kt & 1;
        asm volatile("s_waitcnt vmcnt(8)" ::: "memory");   // kt landed; kt+1 in flight
        __builtin_amdgcn_s_barrier();

        frag_ab b0[4], b1[4];
        #pragma unroll
        for (int ni = 0; ni < 4; ++ni) {
            int row = wn + ni * 16 + fr;
            b0[ni] = *(const frag_ab*)(&Bs[d][row * 64 + ((kq       ^ (row & 7)) * 8)]);
            b1[ni] = *(const frag_ab*)(&Bs[d][row * 64 + (((4 + kq) ^ (row & 7)) * 8)]);
        }
        // mi 0..3
        frag_ab alo0[4], alo1[4];
        #pragma unroll
        for (int mi = 0; mi < 4; ++mi) {
            int row = wm + mi * 16 + fr;
            alo0[mi] = *(const frag_ab*)(&As[d][row * 64 + ((kq       ^ (row & 7)) * 8)]);
            alo1[mi] = *(const frag_ab*)(&As[d][row * 64 + (((4 + kq) ^ (row & 7)) * 8)]);
        }
        __builtin_amdgcn_s_setprio(1);
        #pragma unroll
        for (int mi = 0; mi < 4; ++mi)
            #pragma unroll
            for (int ni = 0; ni < 4; ++ni) {
                acc[mi][ni] = __builtin_amdgcn_mfma_f32_16x16x32_bf16(alo0[mi], b0[ni], acc[mi][ni], 0, 0, 0);
                acc[mi][ni] = __builtin_amdgcn_mfma_f32_16x16x32_bf16(alo1[mi], b1[ni], acc[mi][ni], 0, 0, 0);
            }
        __builtin_amdgcn_s_setprio(0);
        // mi 4..7
        frag_ab ahi0[4], ahi1[4];
        #pragma unroll
        for (int mi = 0; mi < 4; ++mi) {
            int row = wm + (mi + 4) * 16 + fr;
            ahi0[mi] = *(const frag_ab*)(&As[d][row * 64 + ((kq       ^ (row & 7)) * 8)]);
            ahi1[mi] = *(const frag_ab*)(&As[d][row * 64 + (((4 + kq) ^ (row & 7)) * 8)]);
        }
        asm volatile("s_waitcnt lgkmcnt(0)" ::: "memory"); // all our reads of buf[d] done
        __builtin_amdgcn_s_barrier();                      // ... and everyone else's
        if (kt < 14) { STAGE(d, kt + 2); }                 // refill buf[d]; 16 in flight
        __builtin_amdgcn_s_setprio(1);
        #pragma unroll
        for (int mi = 0; mi < 4; ++mi)
            #pragma unroll
            for (int ni = 0; ni < 4; ++ni) {
                acc[mi + 4][ni] = __builtin_amdgcn_mfma_f32_16x16x32_bf16(ahi0[mi], b0[ni], acc[mi + 4][ni], 0, 0, 0);
                acc[mi + 4][ni] = __builtin_amdgcn_mfma_f32_16x16x32_bf16(ahi1[mi], b1[ni], acc[mi + 4][ni], 0, 0, 0);
            }
        __builtin_amdgcn_s_setprio(0);
    }

    // peeled last K-tile (kt = 15, buffer 1): drain fully
    {
        asm volatile("s_waitcnt vmcnt(0)" ::: "memory");
        __builtin_amdgcn_s_barrier();
        frag_ab b0[4], b1[4];
        #pragma unroll
        for (int ni = 0; ni < 4; ++ni) {
            int row = wn + ni * 16 + fr;
            b0[ni] = *(const frag_ab*)(&Bs[1][row * 64 + ((kq       ^ (row & 7)) * 8)]);
            b1[ni] = *(const frag_ab*)(&Bs[1][row * 64 + (((4 + kq) ^ (row & 7)) * 8)]);
        }
        #pragma unroll
        for (int h = 0; h < 2; ++h) {
            frag_ab a0[4], a1[4];
            #pragma unroll
            for (int mi = 0; mi < 4; ++mi) {
                int row = wm + (mi + h * 4) * 16 + fr;
                a0[mi] = *(const frag_ab*)(&As[1][row * 64 + ((kq       ^ (row & 7)) * 8)]);
                a1[mi] = *(const frag_ab*)(&As[1][row * 64 + (((4 + kq) ^ (row & 7)) * 8)]);
            }
            __builtin_amdgcn_s_setprio(1);
            #pragma unroll
            for (int mi = 0; mi < 4; ++mi)
                #pragma unroll
                for (int ni = 0; ni < 4; ++ni) {
                    acc[mi + h * 4][ni] = __builtin_amdgcn_mfma_f32_16x16x32_bf16(a0[mi], b0[ni], acc[mi + h * 4][ni], 0, 0, 0);
                    acc[mi + h * 4][ni] = __builtin_amdgcn_mfma_f32_16x16x32_bf16(a1[mi], b1[ni], acc[mi + h * 4][ni], 0, 0, 0);
                }
            __builtin_amdgcn_s_setprio(0);
        }
    }

    // epilogue
    const int colb = lane & 15, rb = (lane >> 4) * 4;
    #pragma unroll
    for (int ni = 0; ni < 4; ++ni) {
        const int col = n0 + wn + ni * 16 + colb;
        const float bias = bo[col];
        #pragma unroll
        for (int mi = 0; mi < 8; ++mi) {
            #pragma unroll
            for (int r = 0; r < 4; ++r) {
                const int row = m0 + wm + mi * 16 + rb + r;
                out[(size_t)row * DIM + col] = acc[mi][ni][r] + bias;
            }
        }
    }
}

// ---------- launch ----------
extern "C" void kernel_launch(void* const* d_in, const int* in_sizes, int n_in,
                              void* d_out, int out_size, void* d_ws, size_t ws_size,
                              hipStream_t stream) {
    const float* x  = (const float*)d_in[0];
    const float* w2 = (const float*)d_in[1];
    const float* b2 = (const float*)d_in[2];
    const float* wo = (const float*)d_in[3];
    const float* bo = (const float*)d_in[4];
    float* out = (float*)d_out;

    char* ws = (char*)d_ws;
    float*          cws = (float*)ws;                                // 655,360 B
    unsigned short* wob = (unsigned short*)(ws + 655360);            // 2 MB
    unsigned short* ybf = (unsigned short*)(ws + 655360 + 2097152);  // 32 MB
    unsigned short* w2b = (unsigned short*)(ws + 655360 + 2097152 + 33554432); // 192 KB

    cvt_w2_kernel<<<NATTP * DIM / 4 / 256, 256, 0, stream>>>(w2, w2b);
    cvt_wo_kernel<<<(DIM * DIM / 4) / 256, 256, 0, stream>>>(wo, wob);
    att_coeff_kernel<<<NTOK / 16, 256, 0, stream>>>(x, w2b, b2, cws);
    y_kernel<<<NTOK / TT, 256, 0, stream>>>(x, cws, ybf);
    gemm_kernel<<<NTOK / GBM * (DIM / GBN), 512, 0, stream>>>(ybf, wob, bo, out);
}